// Round 8
// baseline (415.601 us; speedup 1.0000x reference)
//
#include <hip/hip_runtime.h>
#include <hip/hip_bf16.h>

// MockLlamaAttention R8: B=1, S=2048, HIDDEN=4096, H=32, HKV=8, D=128, G=4.
// Changes vs R7: GEMM rewritten as true counted-vmcnt 8-phase pipeline (T3+T4):
// half-tile LDS recycling lets stages land 2-7 phases ahead; vmcnt(4) once per
// K-tile, never 0 in main loop (m218: counted-vs-drain0 = +38-73%). Per-wave
// reads only its own A-half/B-half, enabling the half-granular ledger:
//   iter i (T0=2i buf0, T1=2i+1 buf1), one half-stage (2 gloads) per phase:
//   ph0:B0(T1) ph1:B1(T1) ph2:A0(T0+2) ph3:A1(T0+2)+vm4
//   ph4:B0(T0+2) ph5:B1(T0+2) ph6:A0(T1+2) ph7:A1(T1+2)+vm4
// Attention / RoPE / cvts unchanged from R7. Workspace: 89 MiB peak.

typedef _Float16 half4_t __attribute__((ext_vector_type(4)));
typedef _Float16 half8_t __attribute__((ext_vector_type(8)));
typedef float f32x4 __attribute__((ext_vector_type(4)));

#define S_LEN 2048
#define HID 4096
#define NH 32
#define NKV 8

__device__ __forceinline__ void gload_lds16(const void* g, void* l) {
  __builtin_amdgcn_global_load_lds((const __attribute__((address_space(1))) void*)g,
                                   (__attribute__((address_space(3))) void*)l, 16, 0, 0);
}

// ---------------- fp32 -> f16 convert (vectorized) ----------------
__global__ __launch_bounds__(256) void cvt_f32_f16(const float* __restrict__ src,
                                                   _Float16* __restrict__ dst, int n4) {
  int i = blockIdx.x * 256 + threadIdx.x;
  if (i >= n4) return;
  f32x4 v = *(const f32x4*)(src + (size_t)i * 4);
  half4_t h = {(_Float16)v[0], (_Float16)v[1], (_Float16)v[2], (_Float16)v[3]};
  *(half4_t*)(dst + (size_t)i * 4) = h;
}

// ------- merged wq|wk|wv fp32 -> contiguous f16 [6144][4096] -------
__global__ __launch_bounds__(256) void cvt_qkv(const float* __restrict__ wq,
                                               const float* __restrict__ wk,
                                               const float* __restrict__ wv,
                                               _Float16* __restrict__ dst, int n4) {
  int i = blockIdx.x * 256 + threadIdx.x;  // n4 = 6144*4096/4
  if (i >= n4) return;
  size_t e = (size_t)i * 4;
  const float* src;
  size_t off;
  if (e < (size_t)4096 * 4096)      { src = wq; off = e; }
  else if (e < (size_t)5120 * 4096) { src = wk; off = e - (size_t)4096 * 4096; }
  else                              { src = wv; off = e - (size_t)5120 * 4096; }
  f32x4 v = *(const f32x4*)(src + off);
  half4_t h = {(_Float16)v[0], (_Float16)v[1], (_Float16)v[2], (_Float16)v[3]};
  *(half4_t*)(dst + e) = h;
}

// ---------------- RoPE cos/sin table: [2048][64] fp32 ----------------
__global__ __launch_bounds__(256) void rope_table_kernel(float* __restrict__ cost,
                                                         float* __restrict__ sint) {
  int i = blockIdx.x * 256 + threadIdx.x;
  int d = i & 63;
  int s = i >> 6;
  float inv = exp2f(-(float)d * (13.287712379549449f / 64.0f));
  float f = (float)s * inv;
  cost[i] = cosf(f);
  sint[i] = sinf(f);
}

// ---------------- RoPE apply for Q (in place, [S][NH*128]) ----------------
__global__ __launch_bounds__(256) void rope_apply_q(_Float16* __restrict__ X,
                                                    const float* __restrict__ cost,
                                                    const float* __restrict__ sint) {
  int idx = blockIdx.x * 256 + threadIdx.x;
  int g = idx & 15;
  int tmp = idx >> 4;
  int h = tmp % NH;
  int s = tmp / NH;
  int d0 = g * 4;
  size_t base = (size_t)s * HID + h * 128 + d0;
  half4_t x1 = *(half4_t*)(X + base);
  half4_t x2 = *(half4_t*)(X + base + 64);
  const float* cp = cost + s * 64 + d0;
  const float* sp = sint + s * 64 + d0;
  half4_t y1, y2;
#pragma unroll
  for (int j = 0; j < 4; ++j) {
    float c = cp[j], sn = sp[j];
    float a = (float)x1[j], b = (float)x2[j];
    y1[j] = (_Float16)(a * c - b * sn);
    y2[j] = (_Float16)(b * c + a * sn);
  }
  *(half4_t*)(X + base) = y1;
  *(half4_t*)(X + base + 64) = y2;
}

// ------- RoPE apply for K, in place on tiled K2 [NKV][S/16][d/8][16s][8d] ----
__global__ __launch_bounds__(256) void rope_k2_inplace(_Float16* __restrict__ K2,
                                                       const float* __restrict__ cost,
                                                       const float* __restrict__ sint) {
  int idx = blockIdx.x * 256 + threadIdx.x;  // S*NKV*16
  int g = idx & 15;
  int tmp = idx >> 4;
  int h = tmp % NKV;
  int s = tmp / NKV;
  int d0 = g * 4;
  size_t tb = (size_t)h * (S_LEN * 128) + (size_t)(s >> 4) * 2048 + (size_t)(s & 15) * 8;
  size_t a1 = tb + (size_t)(d0 >> 3) * 128 + (d0 & 7);
  size_t a2 = a1 + 1024;
  half4_t x1 = *(half4_t*)(K2 + a1);
  half4_t x2 = *(half4_t*)(K2 + a2);
  const float* cp = cost + s * 64 + d0;
  const float* sp = sint + s * 64 + d0;
  half4_t y1, y2;
#pragma unroll
  for (int j = 0; j < 4; ++j) {
    float c = cp[j], sn = sp[j];
    float a = (float)x1[j], b = (float)x2[j];
    y1[j] = (_Float16)(a * c - b * sn);
    y2[j] = (_Float16)(b * c + a * sn);
  }
  *(half4_t*)(K2 + a1) = y1;
  *(half4_t*)(K2 + a2) = y2;
}

// ======== GEMM: 256x256 tile, BK=64, 8 waves, counted-vmcnt 8-phase ========
// C[M,N] = A[M,4096]f16 @ W[N,4096]f16^T. Per wave: 128x64 out (8x4 frags).
// LDS 128 KiB: As/Bs[2 tile-parity][2 half][128*64], XOR swizzle (c8 ^= r&7)
// via inverse-swizzled GLOBAL source + linear gload_lds dest + swizzled read.
// MODE 0: QKV epilogue (cols<4096 Q natural, <5120 K2 tiled, else V2 tiled).
// MODE 1: f32 C [2048][4096].
template <int MODE>
__global__ __launch_bounds__(512, 1) void gemmP(const _Float16* __restrict__ A,
                                                const _Float16* __restrict__ W,
                                                void* __restrict__ out,
                                                _Float16* __restrict__ K2,
                                                _Float16* __restrict__ V2) {
  __shared__ __align__(16) _Float16 As[2][2][128 * 64];
  __shared__ __align__(16) _Float16 Bs[2][2][128 * 64];
  const int t = threadIdx.x;
  const int wid = t >> 6, l = t & 63, lr = l & 15, lg = l >> 4;
  const int wm = wid >> 2, wn = wid & 3;
  const int m0 = blockIdx.y * 256, n0 = blockIdx.x * 256;

  const _Float16* Abase = A + (size_t)m0 * 4096;
  const _Float16* Wbase = W + (size_t)n0 * 4096;

  f32x4 acc[8][4] = {};
  half8_t af[8][2], bf[4][2];

  const int ciw0 = wid * 64;        // wave-uniform LDS chunk bases (16B units)
  const int ciw1 = 512 + wid * 64;

// one half-tile stage = 2 gloads; dest wave-uniform + lane*16 (m104 semantics)
#define STAGE_AH(buf_, hh_, kb_)                                                         \
  {                                                                                      \
    { const int ci = ciw0 + l, r = ci >> 3, c8 = ci & 7;                                 \
      gload_lds16(Abase + (size_t)((hh_)*128 + r) * 4096 + (kb_) + ((c8 ^ (r & 7)) << 3),\
                  &As[buf_][hh_][ciw0 * 8]); }                                           \
    { const int ci = ciw1 + l, r = ci >> 3, c8 = ci & 7;                                 \
      gload_lds16(Abase + (size_t)((hh_)*128 + r) * 4096 + (kb_) + ((c8 ^ (r & 7)) << 3),\
                  &As[buf_][hh_][ciw1 * 8]); }                                           \
  }
#define STAGE_BH(buf_, hh_, kb_)                                                         \
  {                                                                                      \
    { const int ci = ciw0 + l, r = ci >> 3, c8 = ci & 7;                                 \
      gload_lds16(Wbase + (size_t)((hh_)*128 + r) * 4096 + (kb_) + ((c8 ^ (r & 7)) << 3),\
                  &Bs[buf_][hh_][ciw0 * 8]); }                                           \
    { const int ci = ciw1 + l, r = ci >> 3, c8 = ci & 7;                                 \
      gload_lds16(Wbase + (size_t)((hh_)*128 + r) * 4096 + (kb_) + ((c8 ^ (r & 7)) << 3),\
                  &Bs[buf_][hh_][ciw1 * 8]); }                                           \
  }
#define LDA_L(buf_)                                                                      \
  _Pragma("unroll") for (int mi = 0; mi < 4; ++mi)                                       \
  _Pragma("unroll") for (int kk = 0; kk < 2; ++kk) {                                     \
    const int c8 = (kk * 4 + lg) ^ (lr & 7);                                             \
    af[mi][kk] = *(const half8_t*)&As[buf_][wm][(mi * 16 + lr) * 64 + c8 * 8];           \
  }
#define LDA_H(buf_)                                                                      \
  _Pragma("unroll") for (int mi = 0; mi < 4; ++mi)                                       \
  _Pragma("unroll") for (int kk = 0; kk < 2; ++kk) {                                     \
    const int c8 = (kk * 4 + lg) ^ (lr & 7);                                             \
    af[4 + mi][kk] = *(const half8_t*)&As[buf_][wm][((4 + mi) * 16 + lr) * 64 + c8 * 8]; \
  }
#define LDB_L(buf_)                                                                      \
  _Pragma("unroll") for (int ni = 0; ni < 2; ++ni)                                       \
  _Pragma("unroll") for (int kk = 0; kk < 2; ++kk) {                                     \
    const int c8 = (kk * 4 + lg) ^ (lr & 7);                                             \
    bf[ni][kk] = *(const half8_t*)&Bs[buf_][wn >> 1]                                     \
        [((wn & 1) * 64 + ni * 16 + lr) * 64 + c8 * 8];                                  \
  }
#define LDB_H(buf_)                                                                      \
  _Pragma("unroll") for (int ni = 0; ni < 2; ++ni)                                       \
  _Pragma("unroll") for (int kk = 0; kk < 2; ++kk) {                                     \
    const int c8 = (kk * 4 + lg) ^ (lr & 7);                                             \
    bf[2 + ni][kk] = *(const half8_t*)&Bs[buf_][wn >> 1]                                 \
        [((wn & 1) * 64 + (2 + ni) * 16 + lr) * 64 + c8 * 8];                            \
  }
#define QUAD(mlo_, nlo_)                                                                 \
  _Pragma("unroll") for (int mi = 0; mi < 4; ++mi)                                       \
  _Pragma("unroll") for (int ni = 0; ni < 2; ++ni)                                       \
  _Pragma("unroll") for (int kk = 0; kk < 2; ++kk)                                       \
    acc[(mlo_) + mi][(nlo_) + ni] = __builtin_amdgcn_mfma_f32_16x16x32_f16(              \
        af[(mlo_) + mi][kk], bf[(nlo_) + ni][kk], acc[(mlo_) + mi][(nlo_) + ni], 0, 0, 0);
#define SB __builtin_amdgcn_sched_barrier(0)
#define BARR __builtin_amdgcn_s_barrier()
#define LGKM0 asm volatile("s_waitcnt lgkmcnt(0)" ::: "memory")
#define PRI1 __builtin_amdgcn_s_setprio(1)
#define PRI0 __builtin_amdgcn_s_setprio(0)

  // prologue: tile0 (all 4 halves) + tile1 A-halves; wait tile0, keep A(1) in flight
  STAGE_AH(0, 0, 0) STAGE_AH(0, 1, 0) STAGE_BH(0, 0, 0) STAGE_BH(0, 1, 0)
  STAGE_AH(1, 0, 64) STAGE_AH(1, 1, 64)
  asm volatile("s_waitcnt vmcnt(4)" ::: "memory");
  SB; BARR;

  for (int i = 0; i < 31; ++i) {
    const int kb1 = (2 * i + 1) * 64, kb2 = (2 * i + 2) * 64, kb3 = (2 * i + 3) * 64;
    // ph0: T0 reads (a-lo, b-lo) | stage B0(T1)
    LDA_L(0) LDB_L(0) STAGE_BH(1, 0, kb1)
    SB; BARR; LGKM0; SB;
    PRI1; QUAD(0, 0) PRI0; SB; BARR;
    // ph1: a-hi | stage B1(T1)
    LDA_H(0) STAGE_BH(1, 1, kb1)
    SB; BARR; LGKM0; SB;
    PRI1; QUAD(4, 0) PRI0; SB; BARR;
    // ph2: b-hi | stage A0(T0+2)  [A(T0) fully read after ph1 barrier]
    LDB_H(0) STAGE_AH(0, 0, kb2)
    SB; BARR; LGKM0; SB;
    PRI1; QUAD(0, 2) PRI0; SB; BARR;
    // ph3: stage A1(T0+2); counted wait: need B(T1) landed, allow A(T0+2) in flight
    STAGE_AH(0, 1, kb2)
    SB; BARR;
    PRI1; QUAD(4, 2) PRI0;
    asm volatile("s_waitcnt vmcnt(4)" ::: "memory");
    SB; BARR;
    // ph4: T1 reads | stage B0(T0+2)  [B(T0) fully read after ph2 barrier]
    LDA_L(1) LDB_L(1) STAGE_BH(0, 0, kb2)
    SB; BARR; LGKM0; SB;
    PRI1; QUAD(0, 0) PRI0; SB; BARR;
    // ph5: a-hi | stage B1(T0+2)
    LDA_H(1) STAGE_BH(0, 1, kb2)
    SB; BARR; LGKM0; SB;
    PRI1; QUAD(4, 0) PRI0; SB; BARR;
    // ph6: b-hi | stage A0(T1+2)
    LDB_H(1) STAGE_AH(1, 0, kb3)
    SB; BARR; LGKM0; SB;
    PRI1; QUAD(0, 2) PRI0; SB; BARR;
    // ph7: stage A1(T1+2); counted wait: need A,B(T0+2) landed, allow A(T1+2)
    STAGE_AH(1, 1, kb3)
    SB; BARR;
    PRI1; QUAD(4, 2) PRI0;
    asm volatile("s_waitcnt vmcnt(4)" ::: "memory");
    SB; BARR;
  }
  // peeled last iteration: T0=62, T1=63; stage only B(63); drain once
  {
    const int kb1 = 63 * 64;
    LDA_L(0) LDB_L(0) STAGE_BH(1, 0, kb1)
    SB; BARR; LGKM0; SB;
    PRI1; QUAD(0, 0) PRI0; SB; BARR;
    LDA_H(0) STAGE_BH(1, 1, kb1)
    SB; BARR; LGKM0; SB;
    PRI1; QUAD(4, 0) PRI0; SB; BARR;
    LDB_H(0)
    SB; BARR; LGKM0; SB;
    PRI1; QUAD(0, 2) PRI0; SB; BARR;
    PRI1; QUAD(4, 2) PRI0;
    asm volatile("s_waitcnt vmcnt(0)" ::: "memory");
    SB; BARR;
    LDA_L(1) LDB_L(1)
    SB; BARR; LGKM0; SB;
    PRI1; QUAD(0, 0) PRI0; SB; BARR;
    LDA_H(1)
    SB; BARR; LGKM0; SB;
    PRI1; QUAD(4, 0) PRI0; SB; BARR;
    LDB_H(1)
    SB; BARR; LGKM0; SB;
    PRI1; QUAD(0, 2) PRI0; SB; BARR;
    PRI1; QUAD(4, 2) PRI0;
  }
#undef STAGE_AH
#undef STAGE_BH
#undef LDA_L
#undef LDA_H
#undef LDB_L
#undef LDB_H
#undef QUAD
#undef SB
#undef BARR
#undef LGKM0
#undef PRI1
#undef PRI0

  // epilogue (identical mapping to R7, verified)
  const int grow0 = m0 + wm * 128;
  const int gcol0 = n0 + wn * 64;
#pragma unroll
  for (int mi = 0; mi < 8; ++mi) {
#pragma unroll
    for (int ni = 0; ni < 4; ++ni) {
      const int row = grow0 + mi * 16 + lg * 4;
      const int col = gcol0 + ni * 16 + lr;
      if (MODE == 1) {
#pragma unroll
        for (int i = 0; i < 4; ++i)
          ((float*)out)[(size_t)(row + i) * 4096 + col] = acc[mi][ni][i];
      } else {
        if (col < 4096) {
#pragma unroll
          for (int i = 0; i < 4; ++i)
            ((_Float16*)out)[(size_t)(row + i) * 4096 + col] = (_Float16)acc[mi][ni][i];
        } else if (col < 5120) {  // K2 tiled [NKV][S/16][d/8][16s][8d]
          const int c = col - 4096;
          const int h = c >> 7, d = c & 127;
          const size_t kb2 = (size_t)h * (S_LEN * 128) + (size_t)(row >> 4) * 2048 +
                             (size_t)(d >> 3) * 128 + (d & 7);
#pragma unroll
          for (int i = 0; i < 4; ++i)
            K2[kb2 + ((row + i) & 15) * 8] = (_Float16)acc[mi][ni][i];
        } else {  // V2 tiled [NKV][S/16][128d][16s]
          const int c = col - 5120;
          half4_t o;
#pragma unroll
          for (int i = 0; i < 4; ++i) o[i] = (_Float16)acc[mi][ni][i];
          *(half4_t*)(V2 + (size_t)(c >> 7) * (S_LEN * 128) + (size_t)(row >> 4) * 2048 +
                      (size_t)(c & 127) * 16 + (row & 15)) = o;
        }
      }
    }
  }
}

// ---------------- Flash attention (split-KV, tiled K2/V2) — unchanged ---------
__global__ __launch_bounds__(256) void attn_kernel(const _Float16* __restrict__ Q,
                                                   const _Float16* __restrict__ K2,
                                                   const _Float16* __restrict__ V2,
                                                   _Float16* __restrict__ Op,
                                                   float* __restrict__ Md) {
  const int bid = blockIdx.x;
  const int hk = bid & 7;
  const int split = (bid >> 3) & 1;
  const int qt = 63 - (bid >> 4);
  const int w = threadIdx.x >> 6;
  const int h = hk * 4 + w;
  const int l = threadIdx.x & 63;
  const int lr = l & 15;
  const int lg = l >> 4;
  const float scale = 0.08838834764831845f;
  const float LOG2E = 1.4426950408889634f;
  const float NEG = -1.0e30f;

  const int half_steps = qt + 1;
  const int kt0 = split * half_steps;
  const int kt1 = kt0 + half_steps;

  int sq[2];
  half8_t qf[2][4];
#pragma unroll
  for (int qc = 0; qc < 2; ++qc) {
    sq[qc] = qt * 32 + qc * 16 + lr;
#pragma unroll
    for (int c = 0; c < 4; ++c)
      qf[qc][c] = *(const half8_t*)(Q + (size_t)sq[qc] * HID + h * 128 + c * 32 + lg * 8);
  }
  const _Float16* Kb = K2 + (size_t)hk * (S_LEN * 128);
  const _Float16* Vb = V2 + (size_t)hk * (S_LEN * 128);

  f32x4 acc[8][2] = {};
  float m[2] = {NEG, NEG};
  float den[2] = {0.f, 0.f};

  for (int kt = kt0; kt < kt1; ++kt) {
    half8_t kf[4];
#pragma unroll
    for (int c = 0; c < 4; ++c)
      kf[c] = *(const half8_t*)(Kb + (size_t)kt * 2048 + (c * 4 + lg) * 128 + lr * 8);
    f32x4 s0 = {0.f, 0.f, 0.f, 0.f}, s1 = {0.f, 0.f, 0.f, 0.f};
#pragma unroll
    for (int c = 0; c < 4; ++c) {
      s0 = __builtin_amdgcn_mfma_f32_16x16x32_f16(kf[c], qf[0][c], s0, 0, 0, 0);
      s1 = __builtin_amdgcn_mfma_f32_16x16x32_f16(kf[c], qf[1][c], s1, 0, 0, 0);
    }
    const int kbase = kt * 16 + lg * 4;
    float sc[2][4];
#pragma unroll
    for (int i = 0; i < 4; ++i) {
      sc[0][i] = s0[i] * scale;
      sc[1][i] = s1[i] * scale;
    }
    if (kt >= 2 * qt) {
#pragma unroll
      for (int qc = 0; qc < 2; ++qc)
#pragma unroll
        for (int i = 0; i < 4; ++i)
          if (kbase + i > sq[qc]) sc[qc][i] = NEG;
    }
    half4_t pf[2];
#pragma unroll
    for (int qc = 0; qc < 2; ++qc) {
      float mx = fmaxf(fmaxf(sc[qc][0], sc[qc][1]), fmaxf(sc[qc][2], sc[qc][3]));
      mx = fmaxf(mx, __shfl_xor(mx, 16));
      mx = fmaxf(mx, __shfl_xor(mx, 32));
      if (!__all(mx - m[qc] <= 8.0f)) {  // defer-max (T13)
        float mn = fmaxf(m[qc], mx);
        float corr = exp2f((m[qc] - mn) * LOG2E);
        den[qc] *= corr;
#pragma unroll
        for (int dc = 0; dc < 8; ++dc)
#pragma unroll
          for (int i = 0; i < 4; ++i) acc[dc][qc][i] *= corr;
        m[qc] = mn;
      }
      float ps = 0.f, p[4];
#pragma unroll
      for (int i = 0; i < 4; ++i) {
        p[i] = exp2f((sc[qc][i] - m[qc]) * LOG2E);
        ps += p[i];
      }
      ps += __shfl_xor(ps, 16);
      ps += __shfl_xor(ps, 32);
      den[qc] += ps;
      pf[qc] = (half4_t){(_Float16)p[0], (_Float16)p[1], (_Float16)p[2], (_Float16)p[3]};
    }
#pragma unroll
    for (int dc = 0; dc < 8; ++dc) {
      half4_t vf = *(const half4_t*)(Vb + (size_t)kt * 2048 + (dc * 16 + lr) * 16 + lg * 4);
      acc[dc][0] = __builtin_amdgcn_mfma_f32_16x16x16f16(vf, pf[0], acc[dc][0], 0, 0, 0);
      acc[dc][1] = __builtin_amdgcn_mfma_f32_16x16x16f16(vf, pf[1], acc[dc][1], 0, 0, 0);
    }
  }

  _Float16* Os = Op + (size_t)split * S_LEN * HID;
#pragma unroll
  for (int qc = 0; qc < 2; ++qc) {
    float inv = den[qc] > 0.f ? 1.0f / den[qc] : 0.f;
#pragma unroll
    for (int dc = 0; dc < 8; ++dc) {
      half4_t o;
#pragma unroll
      for (int i = 0; i < 4; ++i) o[i] = (_Float16)(acc[dc][qc][i] * inv);
      *(half4_t*)(Os + (size_t)sq[qc] * HID + h * 128 + dc * 16 + lg * 4) = o;
    }
    if (lg == 0) {
      int mdix = ((split * S_LEN + sq[qc]) * NH + h) * 2;
      Md[mdix] = m[qc];
      Md[mdix + 1] = den[qc];
    }
  }
}

// ---------------- split-KV combine ----------------
__global__ __launch_bounds__(256) void attn_combine(const _Float16* __restrict__ Op,
                                                    const float* __restrict__ Md,
                                                    _Float16* __restrict__ O) {
  const float LOG2E = 1.4426950408889634f;
  int idx = blockIdx.x * 256 + threadIdx.x;
  int dd = (idx & 15) * 8;
  int h = (idx >> 4) & 31;
  int s = idx >> 9;
  int base = (s * NH + h) * 2;
  float m0 = Md[base], den0 = Md[base + 1];
  float m1 = Md[S_LEN * NH * 2 + base], den1 = Md[S_LEN * NH * 2 + base + 1];
  float M = fmaxf(m0, m1);
  float w0 = den0 * exp2f((m0 - M) * LOG2E);
  float w1 = den1 * exp2f((m1 - M) * LOG2E);
  float r = 1.0f / (w0 + w1);
  w0 *= r;
  w1 *= r;
  size_t off = (size_t)s * HID + h * 128 + dd;
  half8_t a = *(const half8_t*)(Op + off);
  half8_t b = *(const half8_t*)(Op + (size_t)S_LEN * HID + off);
  half8_t o;
#pragma unroll
  for (int j = 0; j < 8; ++j) o[j] = (_Float16)(w0 * (float)a[j] + w1 * (float)b[j]);
  *(half8_t*)(O + off) = o;
}

// ---------------- launcher ----------------
extern "C" void kernel_launch(void* const* d_in, const int* in_sizes, int n_in,
                              void* d_out, int out_size, void* d_ws, size_t ws_size,
                              hipStream_t stream) {
  (void)in_sizes; (void)n_in; (void)out_size; (void)ws_size;
  const float* hs = (const float*)d_in[0];
  const float* wq = (const float*)d_in[1];
  const float* wk = (const float*)d_in[2];
  const float* wv = (const float*)d_in[3];
  const float* wo = (const float*)d_in[4];

  char* ws = (char*)d_ws;
  _Float16* hs_h = (_Float16*)(ws);                       // [0,16M): hs f16; later o_h
  _Float16* q_h  = (_Float16*)(ws + (16u << 20));         // [16,32M)
  _Float16* K2   = (_Float16*)(ws + (32u << 20));         // [32,36M): tiled K
  _Float16* V2   = (_Float16*)(ws + (36u << 20));         // [36,40M): tiled V
  float* cost    = (float*)(ws + (40u << 20));            // 512 KiB
  float* sint    = (float*)(ws + (40u << 20) + (512u << 10));
  _Float16* wqkv = (_Float16*)(ws + (41u << 20));         // [41,89M): merged f16 weights
  _Float16* Op   = wqkv;                                  // [41,73M): attn partials (wqkv dead)
  float* Md      = (float*)(ws + (73u << 20));            // [73,75M)
  _Float16* wo_h = wqkv;                                  // [41,73M): wo f16 (Op dead)
  _Float16* o_h  = hs_h;

  cvt_f32_f16<<<8192, 256, 0, stream>>>(hs, hs_h, (S_LEN * HID) / 4);
  rope_table_kernel<<<(S_LEN * 64) / 256, 256, 0, stream>>>(cost, sint);
  cvt_qkv<<<24576, 256, 0, stream>>>(wq, wk, wv, wqkv, (6144 * 4096) / 4);

  // merged QKV projection: 24 col-tiles (16 Q, 4 K, 4 V) x 8 row-tiles
  gemmP<0><<<dim3(24, 8), 512, 0, stream>>>(hs_h, wqkv, q_h, K2, V2);

  rope_apply_q<<<(S_LEN * NH * 16) / 256, 256, 0, stream>>>(q_h, cost, sint);
  rope_k2_inplace<<<(S_LEN * NKV * 16) / 256, 256, 0, stream>>>(K2, cost, sint);

  attn_kernel<<<1024, 256, 0, stream>>>(q_h, K2, V2, Op, Md);
  attn_combine<<<4096, 256, 0, stream>>>(Op, Md, o_h);

  cvt_f32_f16<<<16384, 256, 0, stream>>>(wo, wo_h, (HID * HID) / 4);
  gemmP<1><<<dim3(16, 8), 512, 0, stream>>>(o_h, wo_h, d_out, nullptr, nullptr);
}

// Round 9
// 393.690 us; speedup vs baseline: 1.0557x; 1.0557x over previous
//
#include <hip/hip_runtime.h>
#include <hip/hip_bf16.h>

// MockLlamaAttention R9: B=1, S=2048, HIDDEN=4096, H=32, HKV=8, D=128, G=4.
// Changes vs R8: abandon 256^2/8-phase (grids 192/128 blocks left 25-50% of
// CUs idle; m141-style order-pinning hurt). Back to R5's measured-best 128^2
// BK=32 prefetch-dbuf GEMM, now with fp32 weights converted IN the GEMM's
// B reg-staging (f32x4 loads -> cvt -> ds_write_b128, conflict-free mapping).
// Eliminates cvt_qkv/cvt_wo kernels (~61 us of pure HBM traffic).
// A stays global_load_lds f16. Attention unchanged. Workspace: 75 MiB.

typedef _Float16 half4_t __attribute__((ext_vector_type(4)));
typedef _Float16 half8_t __attribute__((ext_vector_type(8)));
typedef float f32x4 __attribute__((ext_vector_type(4)));

#define S_LEN 2048
#define HID 4096
#define NH 32
#define NKV 8

__device__ __forceinline__ void gload_lds16(const void* g, void* l) {
  __builtin_amdgcn_global_load_lds((const __attribute__((address_space(1))) void*)g,
                                   (__attribute__((address_space(3))) void*)l, 16, 0, 0);
}

// ---------------- fp32 -> f16 convert (vectorized) ----------------
__global__ __launch_bounds__(256) void cvt_f32_f16(const float* __restrict__ src,
                                                   _Float16* __restrict__ dst, int n4) {
  int i = blockIdx.x * 256 + threadIdx.x;
  if (i >= n4) return;
  f32x4 v = *(const f32x4*)(src + (size_t)i * 4);
  half4_t h = {(_Float16)v[0], (_Float16)v[1], (_Float16)v[2], (_Float16)v[3]};
  *(half4_t*)(dst + (size_t)i * 4) = h;
}

// ---------------- RoPE cos/sin table: [2048][64] fp32 ----------------
__global__ __launch_bounds__(256) void rope_table_kernel(float* __restrict__ cost,
                                                         float* __restrict__ sint) {
  int i = blockIdx.x * 256 + threadIdx.x;
  int d = i & 63;
  int s = i >> 6;
  float inv = exp2f(-(float)d * (13.287712379549449f / 64.0f));
  float f = (float)s * inv;
  cost[i] = cosf(f);
  sint[i] = sinf(f);
}

// ---------------- RoPE apply for Q (in place, [S][NH*128]) ----------------
__global__ __launch_bounds__(256) void rope_apply_q(_Float16* __restrict__ X,
                                                    const float* __restrict__ cost,
                                                    const float* __restrict__ sint) {
  int idx = blockIdx.x * 256 + threadIdx.x;
  int g = idx & 15;
  int tmp = idx >> 4;
  int h = tmp % NH;
  int s = tmp / NH;
  int d0 = g * 4;
  size_t base = (size_t)s * HID + h * 128 + d0;
  half4_t x1 = *(half4_t*)(X + base);
  half4_t x2 = *(half4_t*)(X + base + 64);
  const float* cp = cost + s * 64 + d0;
  const float* sp = sint + s * 64 + d0;
  half4_t y1, y2;
#pragma unroll
  for (int j = 0; j < 4; ++j) {
    float c = cp[j], sn = sp[j];
    float a = (float)x1[j], b = (float)x2[j];
    y1[j] = (_Float16)(a * c - b * sn);
    y2[j] = (_Float16)(b * c + a * sn);
  }
  *(half4_t*)(X + base) = y1;
  *(half4_t*)(X + base + 64) = y2;
}

// ------- RoPE apply for K, in place on tiled K2 [NKV][S/16][d/8][16s][8d] ----
__global__ __launch_bounds__(256) void rope_k2_inplace(_Float16* __restrict__ K2,
                                                       const float* __restrict__ cost,
                                                       const float* __restrict__ sint) {
  int idx = blockIdx.x * 256 + threadIdx.x;  // S*NKV*16
  int g = idx & 15;
  int tmp = idx >> 4;
  int h = tmp % NKV;
  int s = tmp / NKV;
  int d0 = g * 4;
  size_t tb = (size_t)h * (S_LEN * 128) + (size_t)(s >> 4) * 2048 + (size_t)(s & 15) * 8;
  size_t a1 = tb + (size_t)(d0 >> 3) * 128 + (d0 & 7);
  size_t a2 = a1 + 1024;
  half4_t x1 = *(half4_t*)(K2 + a1);
  half4_t x2 = *(half4_t*)(K2 + a2);
  const float* cp = cost + s * 64 + d0;
  const float* sp = sint + s * 64 + d0;
  half4_t y1, y2;
#pragma unroll
  for (int j = 0; j < 4; ++j) {
    float c = cp[j], sn = sp[j];
    float a = (float)x1[j], b = (float)x2[j];
    y1[j] = (_Float16)(a * c - b * sn);
    y2[j] = (_Float16)(b * c + a * sn);
  }
  *(half4_t*)(K2 + a1) = y1;
  *(half4_t*)(K2 + a2) = y2;
}

// ======== GEMM: 128x128 tile, BK=32, 4 waves, prefetch-dbuf (R5 core) ========
// C = A[M,4096]f16 @ W[N,4096]fp32^T, W converted to f16 during reg-staging.
// A staged via global_load_lds (f16); B: f32x4 loads -> cvt -> ds_write_b128
// (thread t -> row t>>2, 16B chunk t&3: conflict-free b128 write).
// MODE 0: QKV epilogue (bx<32 Q natural, 32-39 K2 tiled, 40-47 V2 tiled).
// MODE 1: f32 C [2048][4096] (O-projection).
template <int MODE>
__global__ __launch_bounds__(256) void gemmC(const _Float16* __restrict__ A,
                                             const float* __restrict__ W0,
                                             const float* __restrict__ W1,
                                             const float* __restrict__ W2,
                                             void* __restrict__ out,
                                             _Float16* __restrict__ K2,
                                             _Float16* __restrict__ V2) {
  __shared__ __align__(16) _Float16 As[2][128 * 32];
  __shared__ __align__(16) _Float16 Bs[2][128 * 32];
  const int t = threadIdx.x, w = t >> 6, l = t & 63, lr = l & 15, lg = l >> 4;
  const int m0 = blockIdx.y * 128;
  const int bx = blockIdx.x;
  const float* Wp;
  int col0, sel;
  if (MODE == 1) {
    Wp = W0; col0 = bx * 128; sel = 0;
  } else {
    if (bx < 32)      { Wp = W0; col0 = bx * 128; sel = 0; }
    else if (bx < 40) { Wp = W1; col0 = (bx - 32) * 128; sel = 1; }
    else              { Wp = W2; col0 = (bx - 40) * 128; sel = 2; }
  }
  const int wm = (w >> 1) * 64, wn = (w & 1) * 64;
  const int srowA = l >> 2, scolA = (l & 3) * 8;  // A gload mapping (R5-verified)
  const int srowB = t >> 2, scolB = (t & 3) * 8;  // B stage: row 0..63 (+64/round)
  const _Float16* ap = A + (size_t)m0 * 4096 + scolA;
  const float* bp = Wp + (size_t)col0 * 4096 + scolB;

  f32x4 acc[4][4] = {};
  f32x4 br[2][2];  // B prefetch regs: [round][quad]

#define GLOAD_A(buf_, kb_)                                            \
  _Pragma("unroll") for (int it = 0; it < 2; ++it) {                  \
    const int ci = it * 4 + w;                                        \
    const int r = ci * 16 + srowA;                                    \
    gload_lds16(ap + (size_t)r * 4096 + (kb_), &As[buf_][ci * 512]);  \
  }
#define LOAD_B(kb_)                                                   \
  _Pragma("unroll") for (int it = 0; it < 2; ++it) {                  \
    const float* p = bp + (size_t)(it * 64 + srowB) * 4096 + (kb_);   \
    br[it][0] = *(const f32x4*)p;                                     \
    br[it][1] = *(const f32x4*)(p + 4);                               \
  }
#define WRITE_B(buf_)                                                 \
  _Pragma("unroll") for (int it = 0; it < 2; ++it) {                  \
    half8_t hv;                                                       \
    _Pragma("unroll") for (int j = 0; j < 4; ++j) {                   \
      hv[j] = (_Float16)br[it][0][j];                                 \
      hv[4 + j] = (_Float16)br[it][1][j];                             \
    }                                                                 \
    *(half8_t*)&Bs[buf_][(it * 64 + srowB) * 32 + scolB] = hv;        \
  }

  // prologue: tile0 A->LDS, tile0 B regs->LDS, tile1 B regs in flight
  LOAD_B(0)
  GLOAD_A(0, 0)
  WRITE_B(0)
  LOAD_B(32)
  __syncthreads();

  int cur = 0;
  for (int kb = 0; kb < 4096; kb += 32) {
    if (kb + 32 < 4096) {  // stage tile k+1 BEFORE compute (drain after compute)
      WRITE_B(cur ^ 1)
      GLOAD_A(cur ^ 1, kb + 32)
      if (kb + 64 < 4096) LOAD_B(kb + 64)
    }
    half8_t af[4], bf[4];
#pragma unroll
    for (int mi = 0; mi < 4; ++mi)
      af[mi] = *(const half8_t*)&As[cur][(wm + mi * 16 + lr) * 32 + lg * 8];
#pragma unroll
    for (int ni = 0; ni < 4; ++ni)
      bf[ni] = *(const half8_t*)&Bs[cur][(wn + ni * 16 + lr) * 32 + lg * 8];
#pragma unroll
    for (int mi = 0; mi < 4; ++mi)
#pragma unroll
      for (int ni = 0; ni < 4; ++ni)
        acc[mi][ni] = __builtin_amdgcn_mfma_f32_16x16x32_f16(af[mi], bf[ni], acc[mi][ni], 0, 0, 0);
    __syncthreads();
    cur ^= 1;
  }
#undef GLOAD_A
#undef LOAD_B
#undef WRITE_B

  // epilogue (R5-verified mappings)
#pragma unroll
  for (int mi = 0; mi < 4; ++mi) {
#pragma unroll
    for (int ni = 0; ni < 4; ++ni) {
      const int row = m0 + wm + mi * 16 + lg * 4;
      const int col = col0 + wn + ni * 16 + lr;
      if (MODE == 1) {
#pragma unroll
        for (int i = 0; i < 4; ++i)
          ((float*)out)[(size_t)(row + i) * 4096 + col] = acc[mi][ni][i];
      } else if (sel == 0) {
#pragma unroll
        for (int i = 0; i < 4; ++i)
          ((_Float16*)out)[(size_t)(row + i) * 4096 + col] = (_Float16)acc[mi][ni][i];
      } else if (sel == 1) {  // K2 tiled [NKV][S/16][d/8][16s][8d], col local 0..1023
        const int h = col >> 7, d = col & 127;
        const size_t kb2 = (size_t)h * (S_LEN * 128) + (size_t)(row >> 4) * 2048 +
                           (size_t)(d >> 3) * 128 + (d & 7);
#pragma unroll
        for (int i = 0; i < 4; ++i)
          K2[kb2 + ((row + i) & 15) * 8] = (_Float16)acc[mi][ni][i];
      } else {  // V2 tiled [NKV][S/16][128d][16s], col local 0..1023
        half4_t o;
#pragma unroll
        for (int i = 0; i < 4; ++i) o[i] = (_Float16)acc[mi][ni][i];
        *(half4_t*)(V2 + (size_t)(col >> 7) * (S_LEN * 128) + (size_t)(row >> 4) * 2048 +
                    (size_t)(col & 127) * 16 + (row & 15)) = o;
      }
    }
  }
}

// ---------------- Flash attention (split-KV, tiled K2/V2) — unchanged ---------
__global__ __launch_bounds__(256) void attn_kernel(const _Float16* __restrict__ Q,
                                                   const _Float16* __restrict__ K2,
                                                   const _Float16* __restrict__ V2,
                                                   _Float16* __restrict__ Op,
                                                   float* __restrict__ Md) {
  const int bid = blockIdx.x;
  const int hk = bid & 7;
  const int split = (bid >> 3) & 1;
  const int qt = 63 - (bid >> 4);
  const int w = threadIdx.x >> 6;
  const int h = hk * 4 + w;
  const int l = threadIdx.x & 63;
  const int lr = l & 15;
  const int lg = l >> 4;
  const float scale = 0.08838834764831845f;
  const float LOG2E = 1.4426950408889634f;
  const float NEG = -1.0e30f;

  const int half_steps = qt + 1;
  const int kt0 = split * half_steps;
  const int kt1 = kt0 + half_steps;

  int sq[2];
  half8_t qf[2][4];
#pragma unroll
  for (int qc = 0; qc < 2; ++qc) {
    sq[qc] = qt * 32 + qc * 16 + lr;
#pragma unroll
    for (int c = 0; c < 4; ++c)
      qf[qc][c] = *(const half8_t*)(Q + (size_t)sq[qc] * HID + h * 128 + c * 32 + lg * 8);
  }
  const _Float16* Kb = K2 + (size_t)hk * (S_LEN * 128);
  const _Float16* Vb = V2 + (size_t)hk * (S_LEN * 128);

  f32x4 acc[8][2] = {};
  float m[2] = {NEG, NEG};
  float den[2] = {0.f, 0.f};

  for (int kt = kt0; kt < kt1; ++kt) {
    half8_t kf[4];
#pragma unroll
    for (int c = 0; c < 4; ++c)
      kf[c] = *(const half8_t*)(Kb + (size_t)kt * 2048 + (c * 4 + lg) * 128 + lr * 8);
    f32x4 s0 = {0.f, 0.f, 0.f, 0.f}, s1 = {0.f, 0.f, 0.f, 0.f};
#pragma unroll
    for (int c = 0; c < 4; ++c) {
      s0 = __builtin_amdgcn_mfma_f32_16x16x32_f16(kf[c], qf[0][c], s0, 0, 0, 0);
      s1 = __builtin_amdgcn_mfma_f32_16x16x32_f16(kf[c], qf[1][c], s1, 0, 0, 0);
    }
    const int kbase = kt * 16 + lg * 4;
    float sc[2][4];
#pragma unroll
    for (int i = 0; i < 4; ++i) {
      sc[0][i] = s0[i] * scale;
      sc[1][i] = s1[i] * scale;
    }
    if (kt >= 2 * qt) {
#pragma unroll
      for (int qc = 0; qc < 2; ++qc)
#pragma unroll
        for (int i = 0; i < 4; ++i)
          if (kbase + i > sq[qc]) sc[qc][i] = NEG;
    }
    half4_t pf[2];
#pragma unroll
    for (int qc = 0; qc < 2; ++qc) {
      float mx = fmaxf(fmaxf(sc[qc][0], sc[qc][1]), fmaxf(sc[qc][2], sc[qc][3]));
      mx = fmaxf(mx, __shfl_xor(mx, 16));
      mx = fmaxf(mx, __shfl_xor(mx, 32));
      if (!__all(mx - m[qc] <= 8.0f)) {  // defer-max (T13)
        float mn = fmaxf(m[qc], mx);
        float corr = exp2f((m[qc] - mn) * LOG2E);
        den[qc] *= corr;
#pragma unroll
        for (int dc = 0; dc < 8; ++dc)
#pragma unroll
          for (int i = 0; i < 4; ++i) acc[dc][qc][i] *= corr;
        m[qc] = mn;
      }
      float ps = 0.f, p[4];
#pragma unroll
      for (int i = 0; i < 4; ++i) {
        p[i] = exp2f((sc[qc][i] - m[qc]) * LOG2E);
        ps += p[i];
      }
      ps += __shfl_xor(ps, 16);
      ps += __shfl_xor(ps, 32);
      den[qc] += ps;
      pf[qc] = (half4_t){(_Float16)p[0], (_Float16)p[1], (_Float16)p[2], (_Float16)p[3]};
    }
#pragma unroll
    for (int dc = 0; dc < 8; ++dc) {
      half4_t vf = *(const half4_t*)(Vb + (size_t)kt * 2048 + (dc * 16 + lr) * 16 + lg * 4);
      acc[dc][0] = __builtin_amdgcn_mfma_f32_16x16x16f16(vf, pf[0], acc[dc][0], 0, 0, 0);
      acc[dc][1] = __builtin_amdgcn_mfma_f32_16x16x16f16(vf, pf[1], acc[dc][1], 0, 0, 0);
    }
  }

  _Float16* Os = Op + (size_t)split * S_LEN * HID;
#pragma unroll
  for (int qc = 0; qc < 2; ++qc) {
    float inv = den[qc] > 0.f ? 1.0f / den[qc] : 0.f;
#pragma unroll
    for (int dc = 0; dc < 8; ++dc) {
      half4_t o;
#pragma unroll
      for (int i = 0; i < 4; ++i) o[i] = (_Float16)(acc[dc][qc][i] * inv);
      *(half4_t*)(Os + (size_t)sq[qc] * HID + h * 128 + dc * 16 + lg * 4) = o;
    }
    if (lg == 0) {
      int mdix = ((split * S_LEN + sq[qc]) * NH + h) * 2;
      Md[mdix] = m[qc];
      Md[mdix + 1] = den[qc];
    }
  }
}

// ---------------- split-KV combine ----------------
__global__ __launch_bounds__(256) void attn_combine(const _Float16* __restrict__ Op,
                                                    const float* __restrict__ Md,
                                                    _Float16* __restrict__ O) {
  const float LOG2E = 1.4426950408889634f;
  int idx = blockIdx.x * 256 + threadIdx.x;
  int dd = (idx & 15) * 8;
  int h = (idx >> 4) & 31;
  int s = idx >> 9;
  int base = (s * NH + h) * 2;
  float m0 = Md[base], den0 = Md[base + 1];
  float m1 = Md[S_LEN * NH * 2 + base], den1 = Md[S_LEN * NH * 2 + base + 1];
  float M = fmaxf(m0, m1);
  float w0 = den0 * exp2f((m0 - M) * LOG2E);
  float w1 = den1 * exp2f((m1 - M) * LOG2E);
  float r = 1.0f / (w0 + w1);
  w0 *= r;
  w1 *= r;
  size_t off = (size_t)s * HID + h * 128 + dd;
  half8_t a = *(const half8_t*)(Op + off);
  half8_t b = *(const half8_t*)(Op + (size_t)S_LEN * HID + off);
  half8_t o;
#pragma unroll
  for (int j = 0; j < 8; ++j) o[j] = (_Float16)(w0 * (float)a[j] + w1 * (float)b[j]);
  *(half8_t*)(O + off) = o;
}

// ---------------- launcher ----------------
extern "C" void kernel_launch(void* const* d_in, const int* in_sizes, int n_in,
                              void* d_out, int out_size, void* d_ws, size_t ws_size,
                              hipStream_t stream) {
  (void)in_sizes; (void)n_in; (void)out_size; (void)ws_size;
  const float* hs = (const float*)d_in[0];
  const float* wq = (const float*)d_in[1];
  const float* wk = (const float*)d_in[2];
  const float* wv = (const float*)d_in[3];
  const float* wo = (const float*)d_in[4];

  char* ws = (char*)d_ws;
  _Float16* hs_h = (_Float16*)(ws);                       // [0,16M): hs f16; later o_h
  _Float16* q_h  = (_Float16*)(ws + (16u << 20));         // [16,32M)
  _Float16* K2   = (_Float16*)(ws + (32u << 20));         // [32,36M): tiled K
  _Float16* V2   = (_Float16*)(ws + (36u << 20));         // [36,40M): tiled V
  float* cost    = (float*)(ws + (40u << 20));            // 512 KiB
  float* sint    = (float*)(ws + (40u << 20) + (512u << 10));
  _Float16* Op   = (_Float16*)(ws + (41u << 20));         // [41,73M): attn partials
  float* Md      = (float*)(ws + (73u << 20));            // [73,75M)
  _Float16* o_h  = hs_h;

  cvt_f32_f16<<<8192, 256, 0, stream>>>(hs, hs_h, (S_LEN * HID) / 4);
  rope_table_kernel<<<(S_LEN * 64) / 256, 256, 0, stream>>>(cost, sint);

  // merged QKV projection, weights converted in-kernel: 48 col-tiles x 16 rows
  gemmC<0><<<dim3(48, 16), 256, 0, stream>>>(hs_h, wq, wk, wv, q_h, K2, V2);

  rope_apply_q<<<(S_LEN * NH * 16) / 256, 256, 0, stream>>>(q_h, cost, sint);
  rope_k2_inplace<<<(S_LEN * NKV * 16) / 256, 256, 0, stream>>>(K2, cost, sint);

  attn_kernel<<<1024, 256, 0, stream>>>(q_h, K2, V2, Op, Md);
  attn_combine<<<4096, 256, 0, stream>>>(Op, Md, o_h);

  // O-projection, wo converted in-kernel
  gemmC<1><<<dim3(32, 16), 256, 0, stream>>>(o_h, wo, nullptr, nullptr, d_out, nullptr, nullptr);
}